// Round 11
// baseline (468.100 us; speedup 1.0000x reference)
//
#include <hip/hip_runtime.h>

typedef __bf16 bf16_t;
typedef bf16_t bf16x8 __attribute__((ext_vector_type(8)));
typedef float f32x4 __attribute__((ext_vector_type(4)));
typedef unsigned short u16;
typedef unsigned long long u64;

__device__ __forceinline__ u16 f2bf(float f) {
  union { float f; unsigned u; } v; v.f = f;
  unsigned r = v.u + 0x7FFFu + ((v.u >> 16) & 1u);
  return (u16)(r >> 16);
}
__device__ __forceinline__ bf16x8 ld8(const u16* p) {
  return *reinterpret_cast<const bf16x8*>(p);
}
__device__ __forceinline__ void gload_lds16(const void* g, void* l) {
  __builtin_amdgcn_global_load_lds(
      (const __attribute__((address_space(1))) void*)g,
      (__attribute__((address_space(3))) void*)l, 16, 0, 0);
}

struct Ptrs4 { const float* p[4]; };

// ---------------- f32 -> bf16 conversions ----------------
struct CvtJob { const float* s; u16* d; int n; };
struct CvtJobs { CvtJob j[8]; };

__global__ __launch_bounds__(256) void cvt_multi(CvtJobs jobs) {
  CvtJob J = jobs.j[blockIdx.y];
  for (int i = blockIdx.x * 256 + threadIdx.x; i < J.n; i += gridDim.x * 256)
    J.d[i] = f2bf(J.s[i]);
}

// ---------------- batched transpose: in [z][C][N] f32 -> out [z][N][C] bf16 ----
struct TJob { const float* s; u16* d; int C, N, nbx, nbz, off; };
struct TJobs { TJob j[12]; };

__global__ __launch_bounds__(256) void transpose_batch(TJobs J, int nj) {
  int bid = blockIdx.x, ji = 0;
#pragma unroll
  for (int k = 1; k < 12; ++k)
    if (k < nj && bid >= J.j[k].off) ji = k;
  TJob job = J.j[ji];
  int local = bid - job.off;
  int z = local % job.nbz;
  int l2 = local / job.nbz;
  int bx = l2 % job.nbx, by = l2 / job.nbx;
  __shared__ float t[32][33];
  int tx = threadIdx.x & 31, ty = threadIdx.x >> 5;
  int n0 = bx * 32, c0 = by * 32;
  long zi = (long)z * job.C * job.N, zo = (long)z * job.N * job.C;
#pragma unroll
  for (int i = 0; i < 4; ++i)
    t[ty + 8 * i][tx] = job.s[zi + (long)(c0 + ty + 8 * i) * job.N + n0 + tx];
  __syncthreads();
#pragma unroll
  for (int i = 0; i < 4; ++i)
    job.d[zo + (long)(n0 + ty + 8 * i) * job.C + c0 + tx] = f2bf(t[tx][ty + 8 * i]);
}

// ---------------- batched GEMM: C[m][n] = sum_k A[m][k]*X[z][n][k] (+bias[m]) ----
// mode 0: o1 bf16 [z][N][M] (transposed store)
// mode 1: o1 bf16 [z][M][N]
// mode 2: o1 f32  [z][M][N], bias + optional residual res
// mode 3: KV: rows<256 -> o1 = K swizzled 16KB key-tiles [z][N/32]{[32][256] ^((key&7)<<4)}
//             rows>=256 -> o2 = V swizzled 16KB key-tiles [z][N/32]{[256][32] ^((d&7)<<4)}
struct GJob {
  const u16 *A, *X;
  const float *bias, *bias2;
  void *o1, *o2;
  const float* res;
  int M, N, K, nbx, nbz, off, mode;
};
struct GJobs { GJob j[8]; };

__global__ __launch_bounds__(256) void gemm_batch(GJobs J, int nj) {
  int bid = blockIdx.x, ji = 0;
#pragma unroll
  for (int k = 1; k < 8; ++k)
    if (k < nj && bid >= J.j[k].off) ji = k;
  GJob job = J.j[ji];
  int local = bid - job.off;
  const int z = local % job.nbz;
  int l2 = local / job.nbz;
  const int n0 = (l2 % job.nbx) * 64, m0 = (l2 / job.nbx) * 64;
  const int M = job.M, N = job.N, K = job.K;
  const u16* __restrict__ A = job.A;
  const u16* __restrict__ X = job.X;

  __shared__ __attribute__((aligned(16))) u16 As[64][40];
  __shared__ __attribute__((aligned(16))) u16 Bs[64][40];
  const int tid = threadIdx.x;
  const long Xz = (long)z * N * K;
  const int arow = tid >> 2, acol = (tid & 3) * 8;
  const int w = tid >> 6, lane = tid & 63, g = lane >> 4, ln = lane & 15;
  const int wm = (w >> 1) * 32, wn = (w & 1) * 32;
  f32x4 zero = {0.f, 0.f, 0.f, 0.f};
  f32x4 acc[2][2];
#pragma unroll
  for (int i = 0; i < 2; ++i)
#pragma unroll
    for (int j = 0; j < 2; ++j) acc[i][j] = zero;

  for (int k0 = 0; k0 < K; k0 += 32) {
    int4 av = *reinterpret_cast<const int4*>(A + (long)(m0 + arow) * K + k0 + acol);
    int4 bv = *reinterpret_cast<const int4*>(X + Xz + (long)(n0 + arow) * K + k0 + acol);
    __syncthreads();
    *reinterpret_cast<int4*>(&As[arow][acol]) = av;
    *reinterpret_cast<int4*>(&Bs[arow][acol]) = bv;
    __syncthreads();
    bf16x8 a0 = ld8(&As[wm + ln][g * 8]);
    bf16x8 a1 = ld8(&As[wm + 16 + ln][g * 8]);
    bf16x8 b0 = ld8(&Bs[wn + ln][g * 8]);
    bf16x8 b1 = ld8(&Bs[wn + 16 + ln][g * 8]);
    acc[0][0] = __builtin_amdgcn_mfma_f32_16x16x32_bf16(a0, b0, acc[0][0], 0, 0, 0);
    acc[0][1] = __builtin_amdgcn_mfma_f32_16x16x32_bf16(a0, b1, acc[0][1], 0, 0, 0);
    acc[1][0] = __builtin_amdgcn_mfma_f32_16x16x32_bf16(a1, b0, acc[1][0], 0, 0, 0);
    acc[1][1] = __builtin_amdgcn_mfma_f32_16x16x32_bf16(a1, b1, acc[1][1], 0, 0, 0);
  }

#pragma unroll
  for (int i = 0; i < 2; ++i) {
#pragma unroll
    for (int j = 0; j < 2; ++j) {
      int mr0 = m0 + wm + 16 * i + g * 4;
      int nc = n0 + wn + 16 * j + ln;
      if (job.mode == 0) {
        u64 pk = 0;
#pragma unroll
        for (int r = 0; r < 4; ++r) {
          float val = acc[i][j][r] + (job.bias ? job.bias[mr0 + r] : 0.f);
          pk |= (u64)f2bf(val) << (16 * r);
        }
        *reinterpret_cast<u64*>((u16*)job.o1 + ((long)z * N + nc) * M + mr0) = pk;
      } else if (job.mode == 1) {
#pragma unroll
        for (int r = 0; r < 4; ++r) {
          float val = acc[i][j][r] + (job.bias ? job.bias[mr0 + r] : 0.f);
          ((u16*)job.o1)[((long)z * M + mr0 + r) * N + nc] = f2bf(val);
        }
      } else if (job.mode == 2) {
#pragma unroll
        for (int r = 0; r < 4; ++r) {
          long idx = ((long)z * M + mr0 + r) * N + nc;
          float val = acc[i][j][r] + job.bias[mr0 + r];
          if (job.res) val += job.res[idx];
          ((float*)job.o1)[idx] = val;
        }
      } else {
        long tbase = (long)z * N * 256 + (long)(nc >> 5) * 8192;  // u16 elems
        if (mr0 < 256) {
          // K tile: [key 32][ch 256] bf16, byte ^= ((key&7)<<4)
          u64 pk = 0;
#pragma unroll
          for (int r = 0; r < 4; ++r)
            pk |= (u64)f2bf(acc[i][j][r] + job.bias[mr0 + r]) << (16 * r);
          int byteoff = ((nc & 31) * 512 + mr0 * 2) ^ ((nc & 7) << 4);
          *reinterpret_cast<u64*>((char*)job.o1 + tbase * 2 + byteoff) = pk;
        } else {
          // V tile: [d 256][key 32] bf16, byte ^= ((d&7)<<4)
          int d0 = mr0 - 256;
#pragma unroll
          for (int r = 0; r < 4; ++r) {
            int d = d0 + r;
            int byteoff = (d * 64 + (nc & 31) * 2) ^ ((d & 7) << 4);
            *reinterpret_cast<u16*>((char*)job.o2 + tbase * 2 + byteoff) =
                f2bf(acc[i][j][r] + job.bias2[d]);
          }
        }
      }
    }
  }
}

// ---------------- batched flash attention ------------------------------------
// Q: [z][N][256] bf16; K,V: swizzled 16KB key-tiles. O: [z][N][256] bf16.
// Block = 128 thr = 2 waves; EACH WAVE OWNS 32 QUERIES (2x LDS reuse per frag),
// both waves share one K/V stream. Wave0 stages K tile, wave1 stages V tile,
// double-buffered via global_load_lds. No split-K.
struct AJob { const u16 *Q, *K, *V; u16* O; int N, off; };
struct AJobs { AJob j[4]; };

__global__ __launch_bounds__(128, 2) void attn_batch(AJobs J, int nj) {
  __shared__ __attribute__((aligned(16))) char stKV[2][2][16384];  // [buf][K|V]
  __shared__ __attribute__((aligned(16))) u16 Ps[2][32][40];
  int bid = blockIdx.x, ji = 0;
#pragma unroll
  for (int k = 1; k < 4; ++k)
    if (k < nj && bid >= J.j[k].off) ji = k;
  AJob job = J.j[ji];
  int local = bid - job.off;
  const int N = job.N;
  const int nbx = N >> 6;  // 64-query blocks per z
  // z -> XCD-pair pinning (assumes round-robin bid->XCD; perf-only)
  int z, bx;
  if (nbx >= 2) {
    z = (local & 7) >> 1;
    bx = ((local >> 3) << 1) | (local & 1);
  } else {
    z = local & 3;
    bx = 0;
  }
  const int tid = threadIdx.x;
  const int w = tid >> 6, lane = tid & 63;
  const int g = lane >> 4, ln = lane & 15;
  const float scale = 0.0625f;  // 1/sqrt(256)
  const int nt = N >> 5;        // 32-key tiles
  const long tb = (long)z * nt;
  const int qbase = bx * 64 + w * 32;

  // Q as B-fragments: qf[qh][cc], col = query = ln within half qh
  bf16x8 qf[2][8];
#pragma unroll
  for (int qh = 0; qh < 2; ++qh) {
    const u16* qp = job.Q + ((long)z * N + qbase + qh * 16 + ln) * 256 + g * 8;
#pragma unroll
    for (int cc = 0; cc < 8; ++cc) qf[qh][cc] = ld8(qp + cc * 32);
  }
  f32x4 zero = {0.f, 0.f, 0.f, 0.f};
  f32x4 oacc[16][2];
#pragma unroll
  for (int ct = 0; ct < 16; ++ct) {
    oacc[ct][0] = zero;
    oacc[ct][1] = zero;
  }
  float mrow[2] = {-1e30f, -1e30f}, lrow[2] = {0.f, 0.f};

  // wave 0 stages the 16KB K tile; wave 1 stages the 16KB V tile
  const char* gsrc = (const char*)(w ? job.V : job.K);
  auto stage_tile = [&](int buf, int t) {
    const char* gp = gsrc + (tb + t) * 16384 + lane * 16;
    char* lp = &stKV[buf][w][0];
#pragma unroll
    for (int q = 0; q < 16; ++q) gload_lds16(gp + q * 1024, lp + q * 1024);
  };

  stage_tile(0, 0);
  asm volatile("s_waitcnt vmcnt(0)" ::: "memory");
  __syncthreads();

  const int swz = (ln & 7) << 4;
  for (int t = 0; t < nt; ++t) {
    const int buf = t & 1;
    if (t + 1 < nt) stage_tile(buf ^ 1, t + 1);
    const char* Kb = &stKV[buf][0][0];
    const char* Vb = &stKV[buf][1][0];

    // S^T = K . Q^T : s[kh][qh], lane col = query ln, rows = keys
    f32x4 s[2][2];
    s[0][0] = zero; s[0][1] = zero; s[1][0] = zero; s[1][1] = zero;
#pragma unroll
    for (int cc = 0; cc < 8; ++cc) {
      bf16x8 k0 = *reinterpret_cast<const bf16x8*>(Kb + ((ln * 512 + cc * 64 + g * 16) ^ swz));
      bf16x8 k1 = *reinterpret_cast<const bf16x8*>(Kb + (((16 + ln) * 512 + cc * 64 + g * 16) ^ swz));
      s[0][0] = __builtin_amdgcn_mfma_f32_16x16x32_bf16(k0, qf[0][cc], s[0][0], 0, 0, 0);
      s[0][1] = __builtin_amdgcn_mfma_f32_16x16x32_bf16(k0, qf[1][cc], s[0][1], 0, 0, 0);
      s[1][0] = __builtin_amdgcn_mfma_f32_16x16x32_bf16(k1, qf[0][cc], s[1][0], 0, 0, 0);
      s[1][1] = __builtin_amdgcn_mfma_f32_16x16x32_bf16(k1, qf[1][cc], s[1][1], 0, 0, 0);
    }
#pragma unroll
    for (int qh = 0; qh < 2; ++qh) {
      float x[8];
#pragma unroll
      for (int r = 0; r < 4; ++r) { x[r] = s[0][qh][r] * scale; x[4 + r] = s[1][qh][r] * scale; }
      float lm = fmaxf(fmaxf(fmaxf(x[0], x[1]), fmaxf(x[2], x[3])),
                       fmaxf(fmaxf(x[4], x[5]), fmaxf(x[6], x[7])));
      lm = fmaxf(lm, __shfl_xor(lm, 16));
      lm = fmaxf(lm, __shfl_xor(lm, 32));
      if (!__all(lm - mrow[qh] <= 8.0f)) {  // T13 defer-max
        float nm = fmaxf(mrow[qh], lm);
        float fac = __expf(mrow[qh] - nm);
        mrow[qh] = nm;
        lrow[qh] *= fac;
#pragma unroll
        for (int ct = 0; ct < 16; ++ct)
#pragma unroll
          for (int r = 0; r < 4; ++r) oacc[ct][qh][r] *= fac;
      }
      float ps = 0.f;
#pragma unroll
      for (int j2 = 0; j2 < 8; ++j2) { x[j2] = __expf(x[j2] - mrow[qh]); ps += x[j2]; }
      ps += __shfl_xor(ps, 16);
      ps += __shfl_xor(ps, 32);
      lrow[qh] += ps;
      u64 plo = (u64)f2bf(x[0]) | ((u64)f2bf(x[1]) << 16) |
                ((u64)f2bf(x[2]) << 32) | ((u64)f2bf(x[3]) << 48);
      u64 phi = (u64)f2bf(x[4]) | ((u64)f2bf(x[5]) << 16) |
                ((u64)f2bf(x[6]) << 32) | ((u64)f2bf(x[7]) << 48);
      *reinterpret_cast<u64*>(&Ps[w][qh * 16 + ln][g * 4]) = plo;
      *reinterpret_cast<u64*>(&Ps[w][qh * 16 + ln][16 + g * 4]) = phi;
    }
    asm volatile("s_waitcnt lgkmcnt(0)" ::: "memory");
    bf16x8 pa0 = ld8(&Ps[w][ln][g * 8]);
    bf16x8 pa1 = ld8(&Ps[w][16 + ln][g * 8]);
    // O^T += V^T . P^T  (each V frag feeds both query halves)
#pragma unroll
    for (int ct = 0; ct < 16; ++ct) {
      bf16x8 vv = *reinterpret_cast<const bf16x8*>(
          Vb + (((ct * 16 + ln) * 64 + g * 16) ^ swz));
      oacc[ct][0] = __builtin_amdgcn_mfma_f32_16x16x32_bf16(vv, pa0, oacc[ct][0], 0, 0, 0);
      oacc[ct][1] = __builtin_amdgcn_mfma_f32_16x16x32_bf16(vv, pa1, oacc[ct][1], 0, 0, 0);
    }
    asm volatile("s_waitcnt vmcnt(0)" ::: "memory");
    __syncthreads();
  }

#pragma unroll
  for (int qh = 0; qh < 2; ++qh) {
    const float rl = 1.f / lrow[qh];
    u16* Oz = job.O + ((long)z * N + qbase + qh * 16 + ln) * 256;
#pragma unroll
    for (int ct = 0; ct < 16; ++ct) {
      u64 pk = 0;
#pragma unroll
      for (int r = 0; r < 4; ++r) pk |= (u64)f2bf(oacc[ct][qh][r] * rl) << (16 * r);
      *reinterpret_cast<u64*>(Oz + ct * 16 + g * 4) = pk;
    }
  }
}

// ---------------- fused q bias: qeb = q_w @ vp_b + q_b ----------------
__global__ __launch_bounds__(256) void qeb_k(const float* __restrict__ qw,
                                             const float* __restrict__ qb, Ptrs4 vpb,
                                             float* __restrict__ qeb) {
  int o = threadIdx.x;
  int lvl = blockIdx.x;
  const float* vb = vpb.p[lvl];
  float acc = qb[o];
  for (int k = 0; k < 256; ++k) acc += qw[o * 256 + k] * vb[k];
  qeb[lvl * 256 + o] = acc;
}

// ---------------- pooling: t levels -> poolT [b][64 pix][1024 ch] bf16 --------
__global__ __launch_bounds__(256) void pool_k(Ptrs4 ts, u16* __restrict__ poolT) {
  int gt = blockIdx.x * 256 + threadIdx.x;
  int ch = gt & 1023;
  int pix = (gt >> 10) & 63;
  int b = gt >> 16;
  int level = ch >> 8, c = ch & 255;
  int H = 64 >> level;
  int f = H >> 3;
  int py = pix >> 3, px = pix & 7;
  const float* src = ts.p[level] + (((long)b * 256 + c) * H + py * f) * H + px * f;
  float s = 0.f;
  for (int dy = 0; dy < f; ++dy)
    for (int dx = 0; dx < f; ++dx) s += src[dy * H + dx];
  poolT[gt] = f2bf(s / (float)(f * f));
}

// ---------------- BN(train) + relu + GAP : x[4][256][64] -> xp[4][256] --------
__global__ __launch_bounds__(64) void bn_k(const float* __restrict__ x,
                                           const float* __restrict__ gw,
                                           const float* __restrict__ gb,
                                           float* __restrict__ xp) {
  int ch = blockIdx.x, t = threadIdx.x;
  float v[4], s = 0.f, sq = 0.f;
#pragma unroll
  for (int b = 0; b < 4; ++b) {
    v[b] = x[((long)b * 256 + ch) * 64 + t];
    s += v[b];
    sq += v[b] * v[b];
  }
#pragma unroll
  for (int off = 32; off; off >>= 1) {
    s += __shfl_xor(s, off);
    sq += __shfl_xor(sq, off);
  }
  float mu = s * (1.f / 256.f);
  float var = sq * (1.f / 256.f) - mu * mu;
  float rstd = rsqrtf(var + 1e-5f);
  float G = gw[ch], Bb = gb[ch];
#pragma unroll
  for (int b = 0; b < 4; ++b) {
    float y = fmaxf((v[b] - mu) * rstd * G + Bb, 0.f);
#pragma unroll
    for (int off = 32; off; off >>= 1) y += __shfl_xor(y, off);
    if (t == 0) xp[b * 256 + ch] = y * (1.f / 64.f);
  }
}

__global__ __launch_bounds__(256) void fc1_k(const float* __restrict__ xp,
                                             const float* __restrict__ w,
                                             const float* __restrict__ bias,
                                             float* __restrict__ o1) {
  int gt = blockIdx.x * 256 + threadIdx.x;  // 4096 = [b][1024]
  int b = gt >> 10, j = gt & 1023;
  float acc = bias[j];
  const float* wr = w + (long)j * 256;
  const float* xr = xp + b * 256;
  for (int k = 0; k < 256; ++k) acc += xr[k] * wr[k];
  o1[gt] = fmaxf(acc, 0.f);
}

__global__ __launch_bounds__(256) void fc2_k(const float* __restrict__ o1,
                                             const float* __restrict__ w,
                                             const float* __restrict__ bias,
                                             float* __restrict__ out) {
  int gt = blockIdx.x * 256 + threadIdx.x;  // 8192 = [b][2048]
  int b = gt >> 11, o = gt & 2047;
  float acc = bias[o];
  const float* wr = w + (long)o * 1024;
  const float* xr = o1 + b * 1024;
  for (int k = 0; k < 1024; ++k) acc += xr[k] * wr[k];
  out[gt] = acc;
}

extern "C" void kernel_launch(void* const* d_in, const int* in_sizes, int n_in,
                              void* d_out, int out_size, void* d_ws, size_t ws_size,
                              hipStream_t stream) {
  (void)in_sizes; (void)n_in; (void)out_size; (void)ws_size;
  const float *v_in[4], *t_in[4], *vp_w[4], *vp_b[4], *op_w[4], *op_b[4];
  for (int i = 0; i < 4; ++i) {
    v_in[i] = (const float*)d_in[i];
    t_in[i] = (const float*)d_in[4 + i];
    vp_w[i] = (const float*)d_in[8 + 4 * i];
    vp_b[i] = (const float*)d_in[9 + 4 * i];
    op_w[i] = (const float*)d_in[10 + 4 * i];
    op_b[i] = (const float*)d_in[11 + 4 * i];
  }
  const float* q_w = (const float*)d_in[24];
  const float* q_b = (const float*)d_in[25];
  const float* k_w = (const float*)d_in[26];
  const float* k_b = (const float*)d_in[27];
  const float* v_w = (const float*)d_in[28];
  const float* v_b = (const float*)d_in[29];
  const float* sg_w = (const float*)d_in[30];
  const float* sg_b = (const float*)d_in[31];
  const float* bn_g = (const float*)d_in[32];
  const float* bn_b = (const float*)d_in[33];
  const float* fc1_w = (const float*)d_in[34];
  const float* fc1_b = (const float*)d_in[35];
  const float* fc2_w = (const float*)d_in[36];
  const float* fc2_b = (const float*)d_in[37];
  float* out = (float*)d_out;

  const int cin[4] = {64, 128, 256, 512};
  const int NN[4] = {4096, 1024, 256, 64};
  const long NOFF[4] = {0, 4194304, 5242880, 5505024};  // 4*N*256 cumsum
  const long VOFF[4] = {0, 1048576, 1572864, 1835008};  // 4*N*cin cumsum

  char* ws = (char*)d_ws;
  size_t off = 0;
  auto alloc = [&](size_t bytes) {
    void* p = ws + off;
    off += (bytes + 255) & ~(size_t)255;
    return p;
  };
  u16* w_q = (u16*)alloc(65536 * 2);
  u16* w_kv = (u16*)alloc(131072 * 2);
  u16* w_op[4];
  for (int i = 0; i < 4; ++i) w_op[i] = (u16*)alloc((size_t)cin[i] * 256 * 2);
  u16* w_sg = (u16*)alloc(262144 * 2);
  u16* vpwT[4];
  for (int i = 0; i < 4; ++i) vpwT[i] = (u16*)alloc((size_t)cin[i] * 256 * 2);
  u16* qe[4];
  for (int i = 0; i < 4; ++i) qe[i] = (u16*)alloc((size_t)256 * cin[i] * 2);
  float* qeb = (float*)alloc(1024 * 4);
  u16* vT = (u16*)alloc((size_t)1966080 * 2);
  u16* tT = (u16*)alloc((size_t)5570560 * 2);
  u16* QT = (u16*)alloc((size_t)5570560 * 2);
  u16* Kt = (u16*)alloc((size_t)5570560 * 2);
  u16* Vt = (u16*)alloc((size_t)5570560 * 2);
  u16* Ob = (u16*)alloc((size_t)5570560 * 2);
  u16* poolT = (u16*)alloc((size_t)262144 * 2);
  float* xbuf = (float*)alloc((size_t)65536 * 4);
  float* xp = (float*)alloc(1024 * 4);
  float* fc1o = (float*)alloc(4096 * 4);

  // 1) weights -> bf16
  CvtJobs jobs;
  jobs.j[0] = {q_w, w_q, 65536};
  jobs.j[1] = {k_w, w_kv, 65536};
  jobs.j[2] = {v_w, w_kv + 65536, 65536};
  jobs.j[3] = {op_w[0], w_op[0], cin[0] * 256};
  jobs.j[4] = {op_w[1], w_op[1], cin[1] * 256};
  jobs.j[5] = {op_w[2], w_op[2], cin[2] * 256};
  jobs.j[6] = {op_w[3], w_op[3], cin[3] * 256};
  jobs.j[7] = {sg_w, w_sg, 262144};
  cvt_multi<<<dim3(32, 8), 256, 0, stream>>>(jobs);

  // 2) batched transposes: vp_w (4), v (4), t (4)
  {
    TJobs T;
    int boff = 0, nj = 0;
    for (int i = 0; i < 4; ++i) {
      int nbx = cin[i] / 32;
      T.j[nj] = {vp_w[i], vpwT[i], 256, cin[i], nbx, 1, boff};
      boff += nbx * 8;
      ++nj;
    }
    for (int i = 0; i < 4; ++i) {
      int nbx = NN[i] / 32, nby = cin[i] / 32;
      T.j[nj] = {v_in[i], vT + VOFF[i], cin[i], NN[i], nbx, 4, boff};
      boff += nbx * nby * 4;
      ++nj;
    }
    for (int i = 0; i < 4; ++i) {
      int nbx = NN[i] / 32;
      T.j[nj] = {t_in[i], tT + NOFF[i], 256, NN[i], nbx, 4, boff};
      boff += nbx * 8 * 4;
      ++nj;
    }
    transpose_batch<<<boff, 256, 0, stream>>>(T, nj);
  }

  // 3) qe = q_w @ vp_w (4 jobs, mode 1)
  {
    GJobs G;
    int boff = 0;
    for (int i = 0; i < 4; ++i) {
      int nbx = cin[i] / 64;
      G.j[i] = {w_q, vpwT[i], nullptr, nullptr, qe[i], nullptr, nullptr,
                256, cin[i], 256, nbx, 1, boff, 1};
      boff += nbx * 4;
    }
    gemm_batch<<<boff, 256, 0, stream>>>(G, 4);
  }
  Ptrs4 vpbp;
  for (int i = 0; i < 4; ++i) vpbp.p[i] = vp_b[i];
  qeb_k<<<4, 256, 0, stream>>>(q_w, q_b, vpbp, qeb);

  // 4) Q-proj (mode 0) + KV-proj (mode 3) in ONE launch (8 jobs)
  {
    GJobs G;
    int boff = 0, nj = 0;
    for (int i = 0; i < 4; ++i) {
      int nbx = NN[i] / 64;
      G.j[nj] = {qe[i], vT + VOFF[i], qeb + 256 * i, nullptr, QT + NOFF[i], nullptr,
                 nullptr, 256, NN[i], cin[i], nbx, 4, boff, 0};
      boff += nbx * 4 * 4;
      ++nj;
    }
    for (int i = 0; i < 4; ++i) {
      int nbx = NN[i] / 64;
      G.j[nj] = {w_kv, tT + NOFF[i], k_b, v_b, Kt + NOFF[i], Vt + NOFF[i], nullptr,
                 512, NN[i], 256, nbx, 4, boff, 3};
      boff += nbx * 8 * 4;
      ++nj;
    }
    gemm_batch<<<boff, 256, 0, stream>>>(G, 8);
  }

  // 5) attention (4 jobs, one launch, 2-wave blocks of 64 queries)
  {
    AJobs A;
    int boff = 0;
    for (int i = 0; i < 4; ++i) {
      A.j[i] = {QT + NOFF[i], Kt + NOFF[i], Vt + NOFF[i], Ob + NOFF[i], NN[i], boff};
      boff += (NN[i] / 64) * 4;
    }
    attn_batch<<<boff, 128, 0, stream>>>(A, 4);
  }

  // 6) pooling for semantic branch
  Ptrs4 tp;
  for (int i = 0; i < 4; ++i) tp.p[i] = t_in[i];
  pool_k<<<1024, 256, 0, stream>>>(tp, poolT);

  // 7) op-proj + residual (4 jobs) and sg-gemm (1 job), mode 2
  const long enh_off[4] = {8192, 8192 + 1048576, 8192 + 1048576 + 524288,
                           8192 + 1048576 + 524288 + 262144};
  {
    GJobs G;
    int boff = 0;
    for (int i = 0; i < 4; ++i) {
      int nbx = NN[i] / 64, nby = cin[i] / 64;
      G.j[i] = {w_op[i], Ob + NOFF[i], op_b[i], nullptr, out + enh_off[i], nullptr,
                v_in[i], cin[i], NN[i], 256, nbx, 4, boff, 2};
      boff += nbx * nby * 4;
    }
    G.j[4] = {w_sg, poolT, sg_b, nullptr, xbuf, nullptr, nullptr,
              256, 64, 1024, 1, 4, boff, 2};
    boff += 1 * 4 * 4;
    gemm_batch<<<boff, 256, 0, stream>>>(G, 5);
  }

  // 8) semantic tail
  bn_k<<<256, 64, 0, stream>>>(xbuf, bn_g, bn_b, xp);
  fc1_k<<<16, 256, 0, stream>>>(xp, fc1_w, fc1_b, fc1o);
  fc2_k<<<32, 256, 0, stream>>>(fc1o, fc2_w, fc2_b, out);
}

// Round 12
// 396.887 us; speedup vs baseline: 1.1794x; 1.1794x over previous
//
#include <hip/hip_runtime.h>

typedef __bf16 bf16_t;
typedef bf16_t bf16x8 __attribute__((ext_vector_type(8)));
typedef float f32x4 __attribute__((ext_vector_type(4)));
typedef unsigned short u16;
typedef unsigned long long u64;

__device__ __forceinline__ u16 f2bf(float f) {
  union { float f; unsigned u; } v; v.f = f;
  unsigned r = v.u + 0x7FFFu + ((v.u >> 16) & 1u);
  return (u16)(r >> 16);
}
__device__ __forceinline__ bf16x8 ld8(const u16* p) {
  return *reinterpret_cast<const bf16x8*>(p);
}
__device__ __forceinline__ void gload_lds16(const void* g, void* l) {
  __builtin_amdgcn_global_load_lds(
      (const __attribute__((address_space(1))) void*)g,
      (__attribute__((address_space(3))) void*)l, 16, 0, 0);
}

struct Ptrs4 { const float* p[4]; };

// ---------------- f32 -> bf16 conversions ----------------
struct CvtJob { const float* s; u16* d; int n; };
struct CvtJobs { CvtJob j[8]; };

__global__ __launch_bounds__(256) void cvt_multi(CvtJobs jobs) {
  CvtJob J = jobs.j[blockIdx.y];
  for (int i = blockIdx.x * 256 + threadIdx.x; i < J.n; i += gridDim.x * 256)
    J.d[i] = f2bf(J.s[i]);
}

// ---------------- batched transpose: in [z][C][N] f32 -> out [z][N][C] bf16 ----
struct TJob { const float* s; u16* d; int C, N, nbx, nbz, off; };
struct TJobs { TJob j[12]; };

__global__ __launch_bounds__(256) void transpose_batch(TJobs J, int nj) {
  int bid = blockIdx.x, ji = 0;
#pragma unroll
  for (int k = 1; k < 12; ++k)
    if (k < nj && bid >= J.j[k].off) ji = k;
  TJob job = J.j[ji];
  int local = bid - job.off;
  int z = local % job.nbz;
  int l2 = local / job.nbz;
  int bx = l2 % job.nbx, by = l2 / job.nbx;
  __shared__ float t[32][33];
  int tx = threadIdx.x & 31, ty = threadIdx.x >> 5;
  int n0 = bx * 32, c0 = by * 32;
  long zi = (long)z * job.C * job.N, zo = (long)z * job.N * job.C;
#pragma unroll
  for (int i = 0; i < 4; ++i)
    t[ty + 8 * i][tx] = job.s[zi + (long)(c0 + ty + 8 * i) * job.N + n0 + tx];
  __syncthreads();
#pragma unroll
  for (int i = 0; i < 4; ++i)
    job.d[zo + (long)(n0 + ty + 8 * i) * job.C + c0 + tx] = f2bf(t[tx][ty + 8 * i]);
}

// ---------------- batched GEMM: C[m][n] = sum_k A[m][k]*X[z][n][k] (+bias[m]) ----
// mode 0: o1 bf16 [z][N][M] (transposed store)
// mode 1: o1 bf16 [z][M][N]
// mode 2: o1 f32  [z][M][N], bias + optional residual res
// mode 3: KV: rows<256 -> o1 = K swizzled 16KB key-tiles [z][N/32]{[32][256] ^((key&7)<<4)}
//             rows>=256 -> o2 = V swizzled 16KB key-tiles [z][N/32]{[256][32] ^((d&7)<<4)}
struct GJob {
  const u16 *A, *X;
  const float *bias, *bias2;
  void *o1, *o2;
  const float* res;
  int M, N, K, nbx, nbz, off, mode;
};
struct GJobs { GJob j[8]; };

__global__ __launch_bounds__(256) void gemm_batch(GJobs J, int nj) {
  int bid = blockIdx.x, ji = 0;
#pragma unroll
  for (int k = 1; k < 8; ++k)
    if (k < nj && bid >= J.j[k].off) ji = k;
  GJob job = J.j[ji];
  int local = bid - job.off;
  const int z = local % job.nbz;
  int l2 = local / job.nbz;
  const int n0 = (l2 % job.nbx) * 64, m0 = (l2 / job.nbx) * 64;
  const int M = job.M, N = job.N, K = job.K;
  const u16* __restrict__ A = job.A;
  const u16* __restrict__ X = job.X;

  __shared__ __attribute__((aligned(16))) u16 As[64][40];
  __shared__ __attribute__((aligned(16))) u16 Bs[64][40];
  const int tid = threadIdx.x;
  const long Xz = (long)z * N * K;
  const int arow = tid >> 2, acol = (tid & 3) * 8;
  const int w = tid >> 6, lane = tid & 63, g = lane >> 4, ln = lane & 15;
  const int wm = (w >> 1) * 32, wn = (w & 1) * 32;
  f32x4 zero = {0.f, 0.f, 0.f, 0.f};
  f32x4 acc[2][2];
#pragma unroll
  for (int i = 0; i < 2; ++i)
#pragma unroll
    for (int j = 0; j < 2; ++j) acc[i][j] = zero;

  for (int k0 = 0; k0 < K; k0 += 32) {
    int4 av = *reinterpret_cast<const int4*>(A + (long)(m0 + arow) * K + k0 + acol);
    int4 bv = *reinterpret_cast<const int4*>(X + Xz + (long)(n0 + arow) * K + k0 + acol);
    __syncthreads();
    *reinterpret_cast<int4*>(&As[arow][acol]) = av;
    *reinterpret_cast<int4*>(&Bs[arow][acol]) = bv;
    __syncthreads();
    bf16x8 a0 = ld8(&As[wm + ln][g * 8]);
    bf16x8 a1 = ld8(&As[wm + 16 + ln][g * 8]);
    bf16x8 b0 = ld8(&Bs[wn + ln][g * 8]);
    bf16x8 b1 = ld8(&Bs[wn + 16 + ln][g * 8]);
    acc[0][0] = __builtin_amdgcn_mfma_f32_16x16x32_bf16(a0, b0, acc[0][0], 0, 0, 0);
    acc[0][1] = __builtin_amdgcn_mfma_f32_16x16x32_bf16(a0, b1, acc[0][1], 0, 0, 0);
    acc[1][0] = __builtin_amdgcn_mfma_f32_16x16x32_bf16(a1, b0, acc[1][0], 0, 0, 0);
    acc[1][1] = __builtin_amdgcn_mfma_f32_16x16x32_bf16(a1, b1, acc[1][1], 0, 0, 0);
  }

#pragma unroll
  for (int i = 0; i < 2; ++i) {
#pragma unroll
    for (int j = 0; j < 2; ++j) {
      int mr0 = m0 + wm + 16 * i + g * 4;
      int nc = n0 + wn + 16 * j + ln;
      if (job.mode == 0) {
        u64 pk = 0;
#pragma unroll
        for (int r = 0; r < 4; ++r) {
          float val = acc[i][j][r] + (job.bias ? job.bias[mr0 + r] : 0.f);
          pk |= (u64)f2bf(val) << (16 * r);
        }
        *reinterpret_cast<u64*>((u16*)job.o1 + ((long)z * N + nc) * M + mr0) = pk;
      } else if (job.mode == 1) {
#pragma unroll
        for (int r = 0; r < 4; ++r) {
          float val = acc[i][j][r] + (job.bias ? job.bias[mr0 + r] : 0.f);
          ((u16*)job.o1)[((long)z * M + mr0 + r) * N + nc] = f2bf(val);
        }
      } else if (job.mode == 2) {
#pragma unroll
        for (int r = 0; r < 4; ++r) {
          long idx = ((long)z * M + mr0 + r) * N + nc;
          float val = acc[i][j][r] + job.bias[mr0 + r];
          if (job.res) val += job.res[idx];
          ((float*)job.o1)[idx] = val;
        }
      } else {
        long tbase = (long)z * N * 256 + (long)(nc >> 5) * 8192;  // u16 elems
        if (mr0 < 256) {
          u64 pk = 0;
#pragma unroll
          for (int r = 0; r < 4; ++r)
            pk |= (u64)f2bf(acc[i][j][r] + job.bias[mr0 + r]) << (16 * r);
          int byteoff = ((nc & 31) * 512 + mr0 * 2) ^ ((nc & 7) << 4);
          *reinterpret_cast<u64*>((char*)job.o1 + tbase * 2 + byteoff) = pk;
        } else {
          int d0 = mr0 - 256;
#pragma unroll
          for (int r = 0; r < 4; ++r) {
            int d = d0 + r;
            int byteoff = (d * 64 + (nc & 31) * 2) ^ ((d & 7) << 4);
            *reinterpret_cast<u16*>((char*)job.o2 + tbase * 2 + byteoff) =
                f2bf(acc[i][j][r] + job.bias2[d]);
          }
        }
      }
    }
  }
}

// ---------------- batched flash attention, split-K across blocks -------------
// Q: [z][N][256] bf16; K,V: swizzled 16KB key-tiles. Writes PARTIALS:
// OP{0,1} bf16 numerators (layout == O), ML{0,1} f32 [row][2] = (m, l).
// Block = 256 thr = 4 waves; wave owns NQH*16 queries; block covers half keys.
struct AJob { const u16 *Q, *K, *V; long noff; int N, off; };
struct AJobs { AJob j[4]; };

template <int NQH>
__global__ __launch_bounds__(256, 1) void attn_part(
    AJobs J, int nj, u16* __restrict__ OP0, u16* __restrict__ OP1,
    float* __restrict__ ML0, float* __restrict__ ML1) {
  __shared__ __attribute__((aligned(16))) char stKV[2][2][16384];  // [buf][K|V]
  __shared__ __attribute__((aligned(16))) u16 Ps[4][32][40];
  int bid = blockIdx.x, ji = 0;
#pragma unroll
  for (int k = 1; k < 4; ++k)
    if (k < nj && bid >= J.j[k].off) ji = k;
  AJob job = J.j[ji];
  int local = bid - job.off;
  const int z = local & 3;          // z fastest: spreads each z across XCDs
  const int r2 = local >> 2;
  const int kseg = r2 & 1, qt = r2 >> 1;
  const int N = job.N;
  const int tid = threadIdx.x;
  const int w = tid >> 6, lane = tid & 63;
  const int g = lane >> 4, ln = lane & 15;
  const float scale = 0.0625f;      // 1/sqrt(256)
  const int nt = N >> 6;            // 32-key tiles per kseg
  const int qbase = qt * (NQH * 64) + w * (NQH * 16);

  // Q as B-fragments: qf[qh][cc], col = query = ln within half qh
  bf16x8 qf[NQH][8];
#pragma unroll
  for (int qh = 0; qh < NQH; ++qh) {
    const u16* qp = job.Q + ((long)z * N + qbase + qh * 16 + ln) * 256 + g * 8;
#pragma unroll
    for (int cc = 0; cc < 8; ++cc) qf[qh][cc] = ld8(qp + cc * 32);
  }
  f32x4 zero = {0.f, 0.f, 0.f, 0.f};
  f32x4 oacc[16][NQH];
#pragma unroll
  for (int ct = 0; ct < 16; ++ct)
#pragma unroll
    for (int qh = 0; qh < NQH; ++qh) oacc[ct][qh] = zero;
  float mrow[NQH], lrow[NQH];
#pragma unroll
  for (int qh = 0; qh < NQH; ++qh) { mrow[qh] = -1e30f; lrow[qh] = 0.f; }

  // staging: waves 0,1 -> K halves; waves 2,3 -> V halves (8KB each)
  const long kvbyte = ((long)z * (N >> 5) + (long)kseg * nt) * 16384;
  const char* gsrc = ((w < 2) ? (const char*)job.K : (const char*)job.V) + kvbyte;
  auto stage_tile = [&](int buf, int t) {
    const char* gp = gsrc + (long)t * 16384 + (w & 1) * 8192 + lane * 16;
    char* lp = &stKV[buf][w >> 1][(w & 1) * 8192];
#pragma unroll
    for (int q = 0; q < 8; ++q) gload_lds16(gp + q * 1024, lp + q * 1024);
  };

  stage_tile(0, 0);
  asm volatile("s_waitcnt vmcnt(0)" ::: "memory");
  __syncthreads();

  const int swz = (ln & 7) << 4;
  for (int t = 0; t < nt; ++t) {
    const int buf = t & 1;
    // T4: issue next tile, wait only for CURRENT tile (8 newest stay in flight)
    if (t + 1 < nt) {
      stage_tile(buf ^ 1, t + 1);
      asm volatile("s_waitcnt vmcnt(8)" ::: "memory");
    } else {
      asm volatile("s_waitcnt vmcnt(0)" ::: "memory");
    }
    __builtin_amdgcn_sched_barrier(0);
    __builtin_amdgcn_s_barrier();
    const char* Kb = &stKV[buf][0][0];
    const char* Vb = &stKV[buf][1][0];

    // S^T = K . Q^T
    f32x4 s[2][NQH];
#pragma unroll
    for (int kh = 0; kh < 2; ++kh)
#pragma unroll
      for (int qh = 0; qh < NQH; ++qh) s[kh][qh] = zero;
    __builtin_amdgcn_s_setprio(1);
#pragma unroll
    for (int cc = 0; cc < 8; ++cc) {
      bf16x8 k0 = *reinterpret_cast<const bf16x8*>(Kb + ((ln * 512 + cc * 64 + g * 16) ^ swz));
      bf16x8 k1 = *reinterpret_cast<const bf16x8*>(Kb + (((16 + ln) * 512 + cc * 64 + g * 16) ^ swz));
#pragma unroll
      for (int qh = 0; qh < NQH; ++qh) {
        s[0][qh] = __builtin_amdgcn_mfma_f32_16x16x32_bf16(k0, qf[qh][cc], s[0][qh], 0, 0, 0);
        s[1][qh] = __builtin_amdgcn_mfma_f32_16x16x32_bf16(k1, qf[qh][cc], s[1][qh], 0, 0, 0);
      }
    }
    __builtin_amdgcn_s_setprio(0);
#pragma unroll
    for (int qh = 0; qh < NQH; ++qh) {
      float x[8];
#pragma unroll
      for (int r = 0; r < 4; ++r) { x[r] = s[0][qh][r] * scale; x[4 + r] = s[1][qh][r] * scale; }
      float lm = fmaxf(fmaxf(fmaxf(x[0], x[1]), fmaxf(x[2], x[3])),
                       fmaxf(fmaxf(x[4], x[5]), fmaxf(x[6], x[7])));
      lm = fmaxf(lm, __shfl_xor(lm, 16));
      lm = fmaxf(lm, __shfl_xor(lm, 32));
      if (!__all(lm - mrow[qh] <= 8.0f)) {  // T13 defer-max
        float nm = fmaxf(mrow[qh], lm);
        float fac = __expf(mrow[qh] - nm);
        mrow[qh] = nm;
        lrow[qh] *= fac;
#pragma unroll
        for (int ct = 0; ct < 16; ++ct)
#pragma unroll
          for (int r = 0; r < 4; ++r) oacc[ct][qh][r] *= fac;
      }
      float ps = 0.f;
#pragma unroll
      for (int j2 = 0; j2 < 8; ++j2) { x[j2] = __expf(x[j2] - mrow[qh]); ps += x[j2]; }
      ps += __shfl_xor(ps, 16);
      ps += __shfl_xor(ps, 32);
      lrow[qh] += ps;
      u64 plo = (u64)f2bf(x[0]) | ((u64)f2bf(x[1]) << 16) |
                ((u64)f2bf(x[2]) << 32) | ((u64)f2bf(x[3]) << 48);
      u64 phi = (u64)f2bf(x[4]) | ((u64)f2bf(x[5]) << 16) |
                ((u64)f2bf(x[6]) << 32) | ((u64)f2bf(x[7]) << 48);
      *reinterpret_cast<u64*>(&Ps[w][qh * 16 + ln][g * 4]) = plo;
      *reinterpret_cast<u64*>(&Ps[w][qh * 16 + ln][16 + g * 4]) = phi;
    }
    asm volatile("s_waitcnt lgkmcnt(0)" ::: "memory");
    bf16x8 pa[NQH];
#pragma unroll
    for (int qh = 0; qh < NQH; ++qh) pa[qh] = ld8(&Ps[w][qh * 16 + ln][g * 8]);
    __builtin_amdgcn_s_setprio(1);
#pragma unroll
    for (int ct = 0; ct < 16; ++ct) {
      bf16x8 vv = *reinterpret_cast<const bf16x8*>(
          Vb + (((ct * 16 + ln) * 64 + g * 16) ^ swz));
#pragma unroll
      for (int qh = 0; qh < NQH; ++qh)
        oacc[ct][qh] = __builtin_amdgcn_mfma_f32_16x16x32_bf16(vv, pa[qh], oacc[ct][qh], 0, 0, 0);
    }
    __builtin_amdgcn_s_setprio(0);
    __builtin_amdgcn_sched_barrier(0);
    __builtin_amdgcn_s_barrier();
  }

  // store partials (unnormalized numerators + m,l)
  u16* OP = kseg ? OP1 : OP0;
  float* ML = kseg ? ML1 : ML0;
#pragma unroll
  for (int qh = 0; qh < NQH; ++qh) {
    const long qrow = (long)z * N + qbase + qh * 16 + ln;
    u16* Oz = OP + job.noff + qrow * 256;
#pragma unroll
    for (int ct = 0; ct < 16; ++ct) {
      u64 pk = 0;
#pragma unroll
      for (int r = 0; r < 4; ++r) pk |= (u64)f2bf(oacc[ct][qh][r]) << (16 * r);
      *reinterpret_cast<u64*>(Oz + ct * 16 + g * 4) = pk;
    }
    if (g == 0) {
      long mlrow = (job.noff >> 8) + qrow;
      ML[mlrow * 2] = mrow[qh];
      ML[mlrow * 2 + 1] = lrow[qh];
    }
  }
}

// ---------------- merge the two key-segment partials -> Ob bf16 --------------
__global__ __launch_bounds__(256) void merge_k(
    const u16* __restrict__ OP0, const u16* __restrict__ OP1,
    const float* __restrict__ ML0, const float* __restrict__ ML1,
    u16* __restrict__ Ob) {
  const int tid = threadIdx.x;
  const long row = (long)blockIdx.x * 8 + (tid >> 5);
  const int c = (tid & 31) * 8;
  float ma = ML0[row * 2], la = ML0[row * 2 + 1];
  float mb = ML1[row * 2], lb = ML1[row * 2 + 1];
  float M = fmaxf(ma, mb);
  float wa = __expf(ma - M), wb = __expf(mb - M);
  float rl = 1.f / (wa * la + wb * lb);
  bf16x8 A = ld8(OP0 + row * 256 + c);
  bf16x8 B = ld8(OP1 + row * 256 + c);
  u64 pk0 = 0, pk1 = 0;
#pragma unroll
  for (int j = 0; j < 4; ++j) {
    float v = (wa * (float)A[j] + wb * (float)B[j]) * rl;
    pk0 |= (u64)f2bf(v) << (16 * j);
  }
#pragma unroll
  for (int j = 0; j < 4; ++j) {
    float v = (wa * (float)A[4 + j] + wb * (float)B[4 + j]) * rl;
    pk1 |= (u64)f2bf(v) << (16 * j);
  }
  *reinterpret_cast<u64*>(Ob + row * 256 + c) = pk0;
  *reinterpret_cast<u64*>(Ob + row * 256 + c + 4) = pk1;
}

// ---------------- fused q bias: qeb = q_w @ vp_b + q_b ----------------
__global__ __launch_bounds__(256) void qeb_k(const float* __restrict__ qw,
                                             const float* __restrict__ qb, Ptrs4 vpb,
                                             float* __restrict__ qeb) {
  int o = threadIdx.x;
  int lvl = blockIdx.x;
  const float* vb = vpb.p[lvl];
  float acc = qb[o];
  for (int k = 0; k < 256; ++k) acc += qw[o * 256 + k] * vb[k];
  qeb[lvl * 256 + o] = acc;
}

// ---------------- pooling: t levels -> poolT [b][64 pix][1024 ch] bf16 --------
__global__ __launch_bounds__(256) void pool_k(Ptrs4 ts, u16* __restrict__ poolT) {
  int gt = blockIdx.x * 256 + threadIdx.x;
  int ch = gt & 1023;
  int pix = (gt >> 10) & 63;
  int b = gt >> 16;
  int level = ch >> 8, c = ch & 255;
  int H = 64 >> level;
  int f = H >> 3;
  int py = pix >> 3, px = pix & 7;
  const float* src = ts.p[level] + (((long)b * 256 + c) * H + py * f) * H + px * f;
  float s = 0.f;
  for (int dy = 0; dy < f; ++dy)
    for (int dx = 0; dx < f; ++dx) s += src[dy * H + dx];
  poolT[gt] = f2bf(s / (float)(f * f));
}

// ---------------- BN(train) + relu + GAP : x[4][256][64] -> xp[4][256] --------
__global__ __launch_bounds__(64) void bn_k(const float* __restrict__ x,
                                           const float* __restrict__ gw,
                                           const float* __restrict__ gb,
                                           float* __restrict__ xp) {
  int ch = blockIdx.x, t = threadIdx.x;
  float v[4], s = 0.f, sq = 0.f;
#pragma unroll
  for (int b = 0; b < 4; ++b) {
    v[b] = x[((long)b * 256 + ch) * 64 + t];
    s += v[b];
    sq += v[b] * v[b];
  }
#pragma unroll
  for (int off = 32; off; off >>= 1) {
    s += __shfl_xor(s, off);
    sq += __shfl_xor(sq, off);
  }
  float mu = s * (1.f / 256.f);
  float var = sq * (1.f / 256.f) - mu * mu;
  float rstd = rsqrtf(var + 1e-5f);
  float G = gw[ch], Bb = gb[ch];
#pragma unroll
  for (int b = 0; b < 4; ++b) {
    float y = fmaxf((v[b] - mu) * rstd * G + Bb, 0.f);
#pragma unroll
    for (int off = 32; off; off >>= 1) y += __shfl_xor(y, off);
    if (t == 0) xp[b * 256 + ch] = y * (1.f / 64.f);
  }
}

__global__ __launch_bounds__(256) void fc1_k(const float* __restrict__ xp,
                                             const float* __restrict__ w,
                                             const float* __restrict__ bias,
                                             float* __restrict__ o1) {
  int gt = blockIdx.x * 256 + threadIdx.x;  // 4096 = [b][1024]
  int b = gt >> 10, j = gt & 1023;
  float acc = bias[j];
  const float* wr = w + (long)j * 256;
  const float* xr = xp + b * 256;
  for (int k = 0; k < 256; ++k) acc += xr[k] * wr[k];
  o1[gt] = fmaxf(acc, 0.f);
}

__global__ __launch_bounds__(256) void fc2_k(const float* __restrict__ o1,
                                             const float* __restrict__ w,
                                             const float* __restrict__ bias,
                                             float* __restrict__ out) {
  int gt = blockIdx.x * 256 + threadIdx.x;  // 8192 = [b][2048]
  int b = gt >> 11, o = gt & 2047;
  float acc = bias[o];
  const float* wr = w + (long)o * 1024;
  const float* xr = o1 + b * 1024;
  for (int k = 0; k < 1024; ++k) acc += xr[k] * wr[k];
  out[gt] = acc;
}

extern "C" void kernel_launch(void* const* d_in, const int* in_sizes, int n_in,
                              void* d_out, int out_size, void* d_ws, size_t ws_size,
                              hipStream_t stream) {
  (void)in_sizes; (void)n_in; (void)out_size; (void)ws_size;
  const float *v_in[4], *t_in[4], *vp_w[4], *vp_b[4], *op_w[4], *op_b[4];
  for (int i = 0; i < 4; ++i) {
    v_in[i] = (const float*)d_in[i];
    t_in[i] = (const float*)d_in[4 + i];
    vp_w[i] = (const float*)d_in[8 + 4 * i];
    vp_b[i] = (const float*)d_in[9 + 4 * i];
    op_w[i] = (const float*)d_in[10 + 4 * i];
    op_b[i] = (const float*)d_in[11 + 4 * i];
  }
  const float* q_w = (const float*)d_in[24];
  const float* q_b = (const float*)d_in[25];
  const float* k_w = (const float*)d_in[26];
  const float* k_b = (const float*)d_in[27];
  const float* v_w = (const float*)d_in[28];
  const float* v_b = (const float*)d_in[29];
  const float* sg_w = (const float*)d_in[30];
  const float* sg_b = (const float*)d_in[31];
  const float* bn_g = (const float*)d_in[32];
  const float* bn_b = (const float*)d_in[33];
  const float* fc1_w = (const float*)d_in[34];
  const float* fc1_b = (const float*)d_in[35];
  const float* fc2_w = (const float*)d_in[36];
  const float* fc2_b = (const float*)d_in[37];
  float* out = (float*)d_out;

  const int cin[4] = {64, 128, 256, 512};
  const int NN[4] = {4096, 1024, 256, 64};
  const long NOFF[4] = {0, 4194304, 5242880, 5505024};  // 4*N*256 cumsum
  const long VOFF[4] = {0, 1048576, 1572864, 1835008};  // 4*N*cin cumsum
  const long TOTROWS = 21760;                           // 5570560/256

  char* ws = (char*)d_ws;
  size_t off = 0;
  auto alloc = [&](size_t bytes) {
    void* p = ws + off;
    off += (bytes + 255) & ~(size_t)255;
    return p;
  };
  u16* w_q = (u16*)alloc(65536 * 2);
  u16* w_kv = (u16*)alloc(131072 * 2);
  u16* w_op[4];
  for (int i = 0; i < 4; ++i) w_op[i] = (u16*)alloc((size_t)cin[i] * 256 * 2);
  u16* w_sg = (u16*)alloc(262144 * 2);
  u16* vpwT[4];
  for (int i = 0; i < 4; ++i) vpwT[i] = (u16*)alloc((size_t)cin[i] * 256 * 2);
  u16* qe[4];
  for (int i = 0; i < 4; ++i) qe[i] = (u16*)alloc((size_t)256 * cin[i] * 2);
  float* qeb = (float*)alloc(1024 * 4);
  u16* vT = (u16*)alloc((size_t)1966080 * 2);
  u16* tT = (u16*)alloc((size_t)5570560 * 2);
  u16* QT = (u16*)alloc((size_t)5570560 * 2);
  u16* Kt = (u16*)alloc((size_t)5570560 * 2);
  u16* Vt = (u16*)alloc((size_t)5570560 * 2);
  u16* Ob = (u16*)alloc((size_t)5570560 * 2);
  u16* OP1 = (u16*)alloc((size_t)5570560 * 2);
  float* ML0 = (float*)alloc((size_t)TOTROWS * 2 * 4);
  float* ML1 = (float*)alloc((size_t)TOTROWS * 2 * 4);
  u16* poolT = (u16*)alloc((size_t)262144 * 2);
  float* xbuf = (float*)alloc((size_t)65536 * 4);
  float* xp = (float*)alloc(1024 * 4);
  float* fc1o = (float*)alloc(4096 * 4);
  u16* OP0 = tT;  // tT is dead after the KV-proj launch; reuse as partial arena

  // 1) weights -> bf16
  CvtJobs jobs;
  jobs.j[0] = {q_w, w_q, 65536};
  jobs.j[1] = {k_w, w_kv, 65536};
  jobs.j[2] = {v_w, w_kv + 65536, 65536};
  jobs.j[3] = {op_w[0], w_op[0], cin[0] * 256};
  jobs.j[4] = {op_w[1], w_op[1], cin[1] * 256};
  jobs.j[5] = {op_w[2], w_op[2], cin[2] * 256};
  jobs.j[6] = {op_w[3], w_op[3], cin[3] * 256};
  jobs.j[7] = {sg_w, w_sg, 262144};
  cvt_multi<<<dim3(32, 8), 256, 0, stream>>>(jobs);

  // 2) batched transposes: vp_w (4), v (4), t (4)
  {
    TJobs T;
    int boff = 0, nj = 0;
    for (int i = 0; i < 4; ++i) {
      int nbx = cin[i] / 32;
      T.j[nj] = {vp_w[i], vpwT[i], 256, cin[i], nbx, 1, boff};
      boff += nbx * 8;
      ++nj;
    }
    for (int i = 0; i < 4; ++i) {
      int nbx = NN[i] / 32, nby = cin[i] / 32;
      T.j[nj] = {v_in[i], vT + VOFF[i], cin[i], NN[i], nbx, 4, boff};
      boff += nbx * nby * 4;
      ++nj;
    }
    for (int i = 0; i < 4; ++i) {
      int nbx = NN[i] / 32;
      T.j[nj] = {t_in[i], tT + NOFF[i], 256, NN[i], nbx, 4, boff};
      boff += nbx * 8 * 4;
      ++nj;
    }
    transpose_batch<<<boff, 256, 0, stream>>>(T, nj);
  }

  // 3) qe = q_w @ vp_w (4 jobs, mode 1)
  {
    GJobs G;
    int boff = 0;
    for (int i = 0; i < 4; ++i) {
      int nbx = cin[i] / 64;
      G.j[i] = {w_q, vpwT[i], nullptr, nullptr, qe[i], nullptr, nullptr,
                256, cin[i], 256, nbx, 1, boff, 1};
      boff += nbx * 4;
    }
    gemm_batch<<<boff, 256, 0, stream>>>(G, 4);
  }
  Ptrs4 vpbp;
  for (int i = 0; i < 4; ++i) vpbp.p[i] = vp_b[i];
  qeb_k<<<4, 256, 0, stream>>>(q_w, q_b, vpbp, qeb);

  // 4) Q-proj (mode 0) + KV-proj (mode 3) in ONE launch (8 jobs)
  {
    GJobs G;
    int boff = 0, nj = 0;
    for (int i = 0; i < 4; ++i) {
      int nbx = NN[i] / 64;
      G.j[nj] = {qe[i], vT + VOFF[i], qeb + 256 * i, nullptr, QT + NOFF[i], nullptr,
                 nullptr, 256, NN[i], cin[i], nbx, 4, boff, 0};
      boff += nbx * 4 * 4;
      ++nj;
    }
    for (int i = 0; i < 4; ++i) {
      int nbx = NN[i] / 64;
      G.j[nj] = {w_kv, tT + NOFF[i], k_b, v_b, Kt + NOFF[i], Vt + NOFF[i], nullptr,
                 512, NN[i], 256, nbx, 4, boff, 3};
      boff += nbx * 8 * 4;
      ++nj;
    }
    gemm_batch<<<boff, 256, 0, stream>>>(G, 8);
  }

  // 5) attention partials: levels 0-2 (NQH=2), level 3 (NQH=1), then merge
  {
    AJobs A;
    int boff = 0;
    for (int i = 0; i < 3; ++i) {
      A.j[i] = {QT + NOFF[i], Kt + NOFF[i], Vt + NOFF[i], NOFF[i], NN[i], boff};
      boff += (NN[i] / 128) * 8;  // qt * kseg(2) * z(4)
    }
    attn_part<2><<<boff, 256, 0, stream>>>(A, 3, OP0, OP1, ML0, ML1);
    AJobs B;
    B.j[0] = {QT + NOFF[3], Kt + NOFF[3], Vt + NOFF[3], NOFF[3], 64, 0};
    attn_part<1><<<8, 256, 0, stream>>>(B, 1, OP0, OP1, ML0, ML1);
    merge_k<<<TOTROWS / 8, 256, 0, stream>>>(OP0, OP1, ML0, ML1, Ob);
  }

  // 6) pooling for semantic branch
  Ptrs4 tp;
  for (int i = 0; i < 4; ++i) tp.p[i] = t_in[i];
  pool_k<<<1024, 256, 0, stream>>>(tp, poolT);

  // 7) op-proj + residual (4 jobs) and sg-gemm (1 job), mode 2
  const long enh_off[4] = {8192, 8192 + 1048576, 8192 + 1048576 + 524288,
                           8192 + 1048576 + 524288 + 262144};
  {
    GJobs G;
    int boff = 0;
    for (int i = 0; i < 4; ++i) {
      int nbx = NN[i] / 64, nby = cin[i] / 64;
      G.j[i] = {w_op[i], Ob + NOFF[i], op_b[i], nullptr, out + enh_off[i], nullptr,
                v_in[i], cin[i], NN[i], 256, nbx, 4, boff, 2};
      boff += nbx * nby * 4;
    }
    G.j[4] = {w_sg, poolT, sg_b, nullptr, xbuf, nullptr, nullptr,
              256, 64, 1024, 1, 4, boff, 2};
    boff += 1 * 4 * 4;
    gemm_batch<<<boff, 256, 0, stream>>>(G, 5);
  }

  // 8) semantic tail
  bn_k<<<256, 64, 0, stream>>>(xbuf, bn_g, bn_b, xp);
  fc1_k<<<16, 256, 0, stream>>>(xp, fc1_w, fc1_b, fc1o);
  fc2_k<<<32, 256, 0, stream>>>(fc1o, fc2_w, fc2_b, out);
}